// Round 3
// baseline (1944.323 us; speedup 1.0000x reference)
//
#include <hip/hip_runtime.h>

typedef _Float16 half_t;
typedef _Float16 half4 __attribute__((ext_vector_type(4)));
typedef _Float16 half8 __attribute__((ext_vector_type(8)));
typedef float floatx4 __attribute__((ext_vector_type(4)));
typedef unsigned long long ull_t;

#define SEQ 256
#define BATCH 64
#define EMB 256
#define HID 512
#define NOUT 18
#define M_TOT (SEQ*BATCH)   // 16384

// rnn_layer geometry
#define KK_REG 13            // K-tiles (of 32) held in registers: k < 416
#define K_REG  (KK_REG*32)   // 416
#define KTAIL  (HID - K_REG) // 96 cols in LDS
#define WROW   104           // LDS W row stride in halfs (96 + 8 pad)
#define HROW   520           // LDS h row stride in halfs (512 + 8 pad)
#define WLDS_BYTES (HID*WROW*2)          // 106496
#define HLDS_BYTES (2*16*HROW*2)         // 33280
#define LDS_BYTES  (WLDS_BYTES + HLDS_BYTES)  // 139776

// ---------------- ws layout (bytes) ----------------
#define O_WHH0_16 0u          // 2*512*512 half = 1048576
#define O_WHH1_16 1048576u    // 1048576
#define O_EMFC16  2097152u    // 65536 half = 131072
#define O_WIH0    2228224u    // 1024*256 half = 524288
#define O_WIH1    2752512u    // 1024*1024 half = 2097152
#define O_FC16    4849664u    // 18*1024 half = 36864
#define O_PE      4886528u    // post_emb 16384*256 half = 8388608
#define O_XP      13275136u   // xp 16384*1024 half = 33554432 (shared by layer0/layer1)
#define O_OUT     46829568u   // 16384*1024 half (out0/out1 aliased; stream-ordered safe)
// total 80384000 bytes

// ---------------- fp32 -> fp16 convert (8 elems/thread) ----------------
__global__ void cvt_f32f16(const float* __restrict__ s, half_t* __restrict__ d, int n8) {
    int i = blockIdx.x * 256 + threadIdx.x;
    if (i < n8) {
        const float4* s4 = (const float4*)s;
        float4 a = s4[2*i], b = s4[2*i+1];
        half8 h;
        h[0]=(_Float16)a.x; h[1]=(_Float16)a.y; h[2]=(_Float16)a.z; h[3]=(_Float16)a.w;
        h[4]=(_Float16)b.x; h[5]=(_Float16)b.y; h[6]=(_Float16)b.z; h[7]=(_Float16)b.w;
        *(half8*)(d + (size_t)i*8) = h;
    }
}

// ---------------- generic NT GEMM: C[m,n] = sum_k A[m,k]*B[n,k] + bias ----------------
template<bool GATHER>
__global__ __launch_bounds__(256)
void gemm_nt(const half_t* __restrict__ A, const float* __restrict__ Atab,
             const int* __restrict__ gidx, const half_t* __restrict__ Bm,
             const float* __restrict__ bias0, const float* __restrict__ bias1,
             half_t* __restrict__ Cout, int M, int N, int K)
{
    __shared__ half8 As8[512];   // 128 x 32 half
    __shared__ half8 Bs8[512];
    half_t* As = (half_t*)As8;
    half_t* Bs = (half_t*)Bs8;

    const int tid  = threadIdx.x;
    const int lane = tid & 63, wid = tid >> 6;
    const int wm = wid >> 1, wn = wid & 1;
    const int ln = lane & 15, hi = lane >> 4;
    const int m0 = blockIdx.x * 128, n0 = blockIdx.y * 128;

    floatx4 acc[4][4] = {};
    const int kTiles = K >> 5;

    for (int kt = 0; kt < kTiles; ++kt) {
        if constexpr (GATHER) {
            int r = tid >> 1, q = tid & 1;
            int row = gidx[m0 + r];
            const float* src = Atab + (size_t)row * EMB + kt*32 + q*16;
            float4 f0 = *(const float4*)(src);
            float4 f1 = *(const float4*)(src + 4);
            float4 f2 = *(const float4*)(src + 8);
            float4 f3 = *(const float4*)(src + 12);
            half8 h0, h1;
            h0[0]=(_Float16)f0.x; h0[1]=(_Float16)f0.y; h0[2]=(_Float16)f0.z; h0[3]=(_Float16)f0.w;
            h0[4]=(_Float16)f1.x; h0[5]=(_Float16)f1.y; h0[6]=(_Float16)f1.z; h0[7]=(_Float16)f1.w;
            h1[0]=(_Float16)f2.x; h1[1]=(_Float16)f2.y; h1[2]=(_Float16)f2.z; h1[3]=(_Float16)f2.w;
            h1[4]=(_Float16)f3.x; h1[5]=(_Float16)f3.y; h1[6]=(_Float16)f3.z; h1[7]=(_Float16)f3.w;
            int c0 = 2*q, c1 = 2*q + 1;
            *(half8*)(As + r*32 + (((c0 + (r>>1)) & 3) * 8)) = h0;
            *(half8*)(As + r*32 + (((c1 + (r>>1)) & 3) * 8)) = h1;
        } else {
            #pragma unroll
            for (int ii = 0; ii < 2; ++ii) {
                int ch = tid + ii*256; int r = ch >> 2, c = ch & 3;
                half8 v = *(const half8*)(A + (size_t)(m0+r)*K + kt*32 + c*8);
                *(half8*)(As + r*32 + (((c + (r>>1)) & 3) * 8)) = v;
            }
        }
        #pragma unroll
        for (int ii = 0; ii < 2; ++ii) {
            int ch = tid + ii*256; int r = ch >> 2, c = ch & 3;
            half8 v = *(const half8*)(Bm + (size_t)(n0+r)*K + kt*32 + c*8);
            *(half8*)(Bs + r*32 + (((c + (r>>1)) & 3) * 8)) = v;
        }
        __syncthreads();

        half8 af[4], bf[4];
        #pragma unroll
        for (int mt = 0; mt < 4; ++mt) {
            int r = wm*64 + mt*16 + ln;
            af[mt] = *(const half8*)(As + r*32 + ((hi + (r>>1)) & 3) * 8);
        }
        #pragma unroll
        for (int nt = 0; nt < 4; ++nt) {
            int r = wn*64 + nt*16 + ln;
            bf[nt] = *(const half8*)(Bs + r*32 + ((hi + (r>>1)) & 3) * 8);
        }
        #pragma unroll
        for (int mt = 0; mt < 4; ++mt)
            #pragma unroll
            for (int nt = 0; nt < 4; ++nt)
                acc[mt][nt] = __builtin_amdgcn_mfma_f32_16x16x32_f16(af[mt], bf[nt], acc[mt][nt], 0, 0, 0);
        __syncthreads();
    }

    #pragma unroll
    for (int mt = 0; mt < 4; ++mt) {
        #pragma unroll
        for (int nt = 0; nt < 4; ++nt) {
            int n = n0 + wn*64 + nt*16 + ln;
            float bv = (bias0 ? bias0[n] : 0.f) + (bias1 ? bias1[n] : 0.f);
            #pragma unroll
            for (int r = 0; r < 4; ++r) {
                int m = m0 + wm*64 + mt*16 + hi*4 + r;
                Cout[(size_t)m*N + n] = (half_t)(acc[mt][nt][r] + bv);
            }
        }
    }
}

// ---------------- persistent bidirectional RNN layer (round 5: latency surgery) ----------------
// grid = 8 blocks (2 dir x 4 batch-groups) x 256 thr, 1 wave/SIMD. Same geometry as round 4.
// Changes vs round 4 (all aimed at exposed-latency, not traffic):
//  - barrier = asm "s_waitcnt lgkmcnt(0); s_barrier": no vmcnt(0) drain of global stores.
//  - global out-stores moved AFTER the barrier (fire-and-forget off the critical path).
//  - acc seeded from xq at step top (epilogue add removed; xq liveness shortened).
//  - explicit 2-deep paired bf prefetch (kk 0..11) + quad-batched W-tail reads, shaped to
//    keep live regs <= ~502 so the scheduler can hold ds_reads in flight.
//  - out/xp addressing strength-reduced to running pointers (+-BATCH*1024 halfs/step).
__global__ __launch_bounds__(256, 1)
void rnn_layer(const half_t* __restrict__ xp, half_t* __restrict__ outbuf,
               const half_t* __restrict__ whh16)
{
    extern __shared__ char smem[];
    half_t* wlds = (half_t*)smem;                  // [512][WROW]
    half_t* hlds = (half_t*)(smem + WLDS_BYTES);   // [2][16][HROW]

    const int bid = blockIdx.x;
    const int dir = bid >> 2;
    const int bg  = bid & 3;
    const int wid = threadIdx.x >> 6;
    const int lane = threadIdx.x & 63;
    const int ln = lane & 15, hi = lane >> 4;

    const half_t* wbase = whh16 + (size_t)dir * HID * HID;

    // A fragments in regs: wave wid owns j rows [wid*128, wid*128+128), k < 416.
    half8 afrag[8][KK_REG];
    #pragma unroll
    for (int mt = 0; mt < 8; ++mt) {
        #pragma unroll
        for (int kk = 0; kk < KK_REG; ++kk)
            afrag[mt][kk] = *(const half8*)(wbase + (size_t)(wid*128 + mt*16 + ln)*HID + kk*32 + hi*8);
    }

    // stage W k-tail [416,512) into LDS: 512 rows x 12 half8
    for (int idx = threadIdx.x; idx < HID*12; idx += 256) {
        int row = idx / 12, c8 = idx % 12;
        *(half8*)(wlds + row*WROW + c8*8) =
            *(const half8*)(wbase + (size_t)row*HID + K_REG + c8*8);
    }
    // zero both h buffers (h_0 = 0)
    for (int i = threadIdx.x; i < HLDS_BYTES/16; i += 256)
        ((uint4*)hlds)[i] = make_uint4(0u,0u,0u,0u);

    const int b = bg*16 + ln;        // this lane's batch column
    const int jq = wid*128 + hi*4;   // j quad base; mt adds 16

    // running pointers (xp and outbuf share the row stride)
    const ptrdiff_t dstep = dir ? -(ptrdiff_t)(BATCH*2*HID) : (ptrdiff_t)(BATCH*2*HID);
    const int t0 = dir ? (SEQ-1) : 0;
    const size_t base0 = ((size_t)(t0*BATCH + b))*(2*HID) + (size_t)dir*HID + jq;
    const half_t* xb = xp + base0;
    half_t*       op = outbuf + base0;

    // prefetch xq for step 0
    half4 xq[8];
    #pragma unroll
    for (int mt = 0; mt < 8; ++mt) xq[mt] = *(const half4*)(xb + mt*16);
    xb += dstep;   // points at t1 (prefetched inside step 0)

    // per-lane LDS bases
    const half_t* hrd0 = hlds + (size_t)ln*HROW + hi*8;          // + cb*16*HROW + kk*32
    half_t*       hwr0 = hlds + (size_t)ln*HROW + jq;            // + nb*16*HROW + mt*16
    const half_t* wrd  = wlds + (size_t)(wid*128 + ln)*WROW + hi*8;  // + mt*16*WROW + kt*32

    __syncthreads();

    int cb = 0;
    for (int step = 0; step < SEQ; ++step) {
        const half_t* hrd = hrd0 + (size_t)cb*16*HROW;

        // seed acc with xq (fp32), freeing xq for next-step prefetch
        floatx4 acc[8];
        #pragma unroll
        for (int mt = 0; mt < 8; ++mt) {
            acc[mt][0] = (float)xq[mt][0]; acc[mt][1] = (float)xq[mt][1];
            acc[mt][2] = (float)xq[mt][2]; acc[mt][3] = (float)xq[mt][3];
        }
        // issue next-step xp loads now; they land during the MFMA phase
        if (step + 1 < SEQ) {
            #pragma unroll
            for (int mt = 0; mt < 8; ++mt) xq[mt] = *(const half4*)(xb + mt*16);
        }
        xb += dstep;

        // ---- kk 0..11: paired, 1-pair lookahead ----
        half8 c0 = *(const half8*)(hrd + 0*32);
        half8 c1 = *(const half8*)(hrd + 1*32);
        #pragma unroll
        for (int g = 0; g < 6; ++g) {
            half8 n0 = *(const half8*)(hrd + (2*g+2)*32);
            half8 n1 = *(const half8*)(hrd + (2*g+3)*32);
            #pragma unroll
            for (int mt = 0; mt < 8; ++mt)
                acc[mt] = __builtin_amdgcn_mfma_f32_16x16x32_f16(afrag[mt][2*g],   c0, acc[mt], 0, 0, 0);
            #pragma unroll
            for (int mt = 0; mt < 8; ++mt)
                acc[mt] = __builtin_amdgcn_mfma_f32_16x16x32_f16(afrag[mt][2*g+1], c1, acc[mt], 0, 0, 0);
            c0 = n0; c1 = n1;
        }
        // here c0 = h[kk=12], c1 = h[kk=13]
        half8 c2 = *(const half8*)(hrd + 14*32);
        half8 c3 = *(const half8*)(hrd + 15*32);
        #pragma unroll
        for (int mt = 0; mt < 8; ++mt)
            acc[mt] = __builtin_amdgcn_mfma_f32_16x16x32_f16(afrag[mt][12], c0, acc[mt], 0, 0, 0);

        // ---- tail kk 13..15: W from LDS, quad-batched reads ----
        #pragma unroll
        for (int kt = 0; kt < 3; ++kt) {
            half8 ch = (kt == 0) ? c1 : (kt == 1) ? c2 : c3;
            {
                half8 w0 = *(const half8*)(wrd + 0*16*WROW + kt*32);
                half8 w1 = *(const half8*)(wrd + 1*16*WROW + kt*32);
                half8 w2 = *(const half8*)(wrd + 2*16*WROW + kt*32);
                half8 w3 = *(const half8*)(wrd + 3*16*WROW + kt*32);
                acc[0] = __builtin_amdgcn_mfma_f32_16x16x32_f16(w0, ch, acc[0], 0, 0, 0);
                acc[1] = __builtin_amdgcn_mfma_f32_16x16x32_f16(w1, ch, acc[1], 0, 0, 0);
                acc[2] = __builtin_amdgcn_mfma_f32_16x16x32_f16(w2, ch, acc[2], 0, 0, 0);
                acc[3] = __builtin_amdgcn_mfma_f32_16x16x32_f16(w3, ch, acc[3], 0, 0, 0);
            }
            {
                half8 w4 = *(const half8*)(wrd + 4*16*WROW + kt*32);
                half8 w5 = *(const half8*)(wrd + 5*16*WROW + kt*32);
                half8 w6 = *(const half8*)(wrd + 6*16*WROW + kt*32);
                half8 w7 = *(const half8*)(wrd + 7*16*WROW + kt*32);
                acc[4] = __builtin_amdgcn_mfma_f32_16x16x32_f16(w4, ch, acc[4], 0, 0, 0);
                acc[5] = __builtin_amdgcn_mfma_f32_16x16x32_f16(w5, ch, acc[5], 0, 0, 0);
                acc[6] = __builtin_amdgcn_mfma_f32_16x16x32_f16(w6, ch, acc[6], 0, 0, 0);
                acc[7] = __builtin_amdgcn_mfma_f32_16x16x32_f16(w7, ch, acc[7], 0, 0, 0);
            }
        }

        // ---- epilogue: hv = relu(acc); LDS h-write; barrier; then global store ----
        const int nb = cb ^ 1;
        half_t* hw = hwr0 + (size_t)nb*16*HROW;
        half4 hv[8];
        #pragma unroll
        for (int mt = 0; mt < 8; ++mt) {
            #pragma unroll
            for (int r = 0; r < 4; ++r)
                hv[mt][r] = (_Float16)fmaxf(acc[mt][r], 0.f);
            if (step + 1 < SEQ) *(half4*)(hw + mt*16) = hv[mt];
        }

        if (step + 1 < SEQ) {
            asm volatile("s_waitcnt lgkmcnt(0)\n\ts_barrier" ::: "memory");
            __builtin_amdgcn_sched_barrier(0);
        }

        // post-barrier: fire-and-forget global stores (drained only at kernel end)
        #pragma unroll
        for (int mt = 0; mt < 8; ++mt)
            *(half4*)(op + mt*16) = hv[mt];
        op += dstep;
        cb = nb;
    }
}

// ---------------- final FC: [16384,1024] x [18,1024]^T + b ----------------
__global__ __launch_bounds__(256)
void fc_kernel(const half_t* __restrict__ X, const half_t* __restrict__ W16,
               const float* __restrict__ bias, float* __restrict__ Y)
{
    __shared__ half8 Ws8[2304];   // 18*1024 half
    half_t* Ws = (half_t*)Ws8;
    for (int ch = threadIdx.x; ch < 2304; ch += 256)
        Ws8[ch] = *(const half8*)(W16 + (size_t)ch*8);
    __syncthreads();

    int wi = threadIdx.x >> 6, lane = threadIdx.x & 63;
    int m = blockIdx.x*4 + wi;
    const half_t* xr = X + (size_t)m*1024 + lane*16;
    half8 x0 = *(const half8*)xr;
    half8 x1 = *(const half8*)(xr + 8);
    float xa[16];
    #pragma unroll
    for (int i = 0; i < 8; ++i) { xa[i] = (float)x0[i]; xa[8+i] = (float)x1[i]; }

    for (int n = 0; n < NOUT; ++n) {
        const half_t* wr = Ws + n*1024 + lane*16;
        half8 w0 = *(const half8*)wr;
        half8 w1 = *(const half8*)(wr + 8);
        float s = 0.f;
        #pragma unroll
        for (int i = 0; i < 8; ++i) s += xa[i]*(float)w0[i] + xa[8+i]*(float)w1[i];
        #pragma unroll
        for (int off = 32; off > 0; off >>= 1) s += __shfl_down(s, off, 64);
        if (lane == 0) Y[(size_t)m*NOUT + n] = s + bias[n];
    }
}

// ---------------- launcher ----------------
extern "C" void kernel_launch(void* const* d_in, const int* in_sizes, int n_in,
                              void* d_out, int out_size, void* d_ws, size_t ws_size,
                              hipStream_t stream)
{
    const int*   text    = (const int*)  d_in[0];
    const float* emb     = (const float*)d_in[1];
    const float* emfc_w  = (const float*)d_in[2];
    const float* emfc_b  = (const float*)d_in[3];
    const float* w_ih0   = (const float*)d_in[4];
    const float* w_hh0   = (const float*)d_in[5];
    const float* b_ih0   = (const float*)d_in[6];
    const float* b_hh0   = (const float*)d_in[7];
    const float* w_ih1   = (const float*)d_in[8];
    const float* w_hh1   = (const float*)d_in[9];
    const float* b_ih1   = (const float*)d_in[10];
    const float* b_hh1   = (const float*)d_in[11];
    const float* fc_w    = (const float*)d_in[12];
    const float* fc_b    = (const float*)d_in[13];
    float* out = (float*)d_out;

    char* ws = (char*)d_ws;
    half_t* whh0_16 = (half_t*)(ws + O_WHH0_16);
    half_t* whh1_16 = (half_t*)(ws + O_WHH1_16);
    half_t* emfc16  = (half_t*)(ws + O_EMFC16);
    half_t* wih0    = (half_t*)(ws + O_WIH0);
    half_t* wih1    = (half_t*)(ws + O_WIH1);
    half_t* fc16    = (half_t*)(ws + O_FC16);
    half_t* pe      = (half_t*)(ws + O_PE);
    half_t* xp      = (half_t*)(ws + O_XP);
    half_t* out0    = (half_t*)(ws + O_OUT);
    half_t* out1    = (half_t*)(ws + O_OUT);   // aliased: out0 dead once xp1 GEMM done

    // one-time: allow 136KB dynamic LDS for rnn_layer (host-side attr; capture-safe)
    static int attr_done = 0;
    if (!attr_done) {
        hipFuncSetAttribute((const void*)rnn_layer,
                            hipFuncAttributeMaxDynamicSharedMemorySize, LDS_BYTES);
        attr_done = 1;
    }

    // 1) weight conversions fp32->fp16
    cvt_f32f16<<<32,  256, 0, stream>>>(emfc_w, emfc16, 8192);
    cvt_f32f16<<<128, 256, 0, stream>>>(w_ih0,  wih0,  32768);
    cvt_f32f16<<<512, 256, 0, stream>>>(w_ih1,  wih1, 131072);
    cvt_f32f16<<<256, 256, 0, stream>>>(w_hh0,  whh0_16, 65536);
    cvt_f32f16<<<256, 256, 0, stream>>>(w_hh1,  whh1_16, 65536);
    cvt_f32f16<<<9,   256, 0, stream>>>(fc_w,   fc16,   2304);

    // 2) post_emb = gather(emb, text) @ emfc_w^T + emfc_b
    gemm_nt<true><<<dim3(M_TOT/128, EMB/128), 256, 0, stream>>>(
        nullptr, emb, text, emfc16, emfc_b, nullptr, pe, M_TOT, EMB, EMB);

    // 3) xp0 = post_emb @ w_ih0^T + (b_ih0 + b_hh0)
    gemm_nt<false><<<dim3(M_TOT/128, (2*HID)/128), 256, 0, stream>>>(
        pe, nullptr, nullptr, wih0, b_ih0, b_hh0, xp, M_TOT, 2*HID, EMB);

    // 4) layer0 recurrence (8 independent blocks, no inter-block sync)
    rnn_layer<<<8, 256, LDS_BYTES, stream>>>(xp, out0, whh0_16);

    // 5) xp1 = out0 @ w_ih1^T + (b_ih1 + b_hh1)
    gemm_nt<false><<<dim3(M_TOT/128, (2*HID)/128), 256, 0, stream>>>(
        out0, nullptr, nullptr, wih1, b_ih1, b_hh1, xp, M_TOT, 2*HID, 2*HID);

    // 6) layer1 recurrence
    rnn_layer<<<8, 256, LDS_BYTES, stream>>>(xp, out1, whh1_16);

    // 7) out = out1 @ fc_w^T + fc_b
    fc_kernel<<<M_TOT/4, 256, 0, stream>>>(out1, fc16, fc_b, out);
}

// Round 4
// 1427.473 us; speedup vs baseline: 1.3621x; 1.3621x over previous
//
#include <hip/hip_runtime.h>

typedef _Float16 half_t;
typedef _Float16 half4 __attribute__((ext_vector_type(4)));
typedef _Float16 half8 __attribute__((ext_vector_type(8)));
typedef float floatx4 __attribute__((ext_vector_type(4)));
typedef unsigned long long ull_t;

#define SEQ 256
#define BATCH 64
#define EMB 256
#define HID 512
#define NOUT 18
#define M_TOT (SEQ*BATCH)   // 16384

// rnn_layer geometry (round 6: 8 waves, 2/SIMD TLP)
#define KK_REG 12            // K-tiles (of 32) in registers: k < 384
#define K_REG  (KK_REG*32)   // 384
#define KTAIL  (HID - K_REG) // 128 cols in LDS
#define WROW   136           // LDS W row stride in halfs (128 + 8 pad)
#define HROW   520           // LDS h row stride in halfs (512 + 8 pad)
#define WLDS_BYTES (HID*WROW*2)          // 139264
#define HLDS_BYTES (16*HROW*2)           // 16640 (SINGLE buffer, in-place + 2 barriers)
#define LDS_BYTES  (WLDS_BYTES + HLDS_BYTES)  // 155904 (<= 163840)

// ---------------- ws layout (bytes) ----------------
#define O_WHH0_16 0u          // 2*512*512 half = 1048576
#define O_WHH1_16 1048576u    // 1048576
#define O_EMFC16  2097152u    // 65536 half = 131072
#define O_WIH0    2228224u    // 1024*256 half = 524288
#define O_WIH1    2752512u    // 1024*1024 half = 2097152
#define O_FC16    4849664u    // 18*1024 half = 36864
#define O_PE      4886528u    // post_emb 16384*256 half = 8388608
#define O_XP      13275136u   // xp 16384*1024 half = 33554432 (shared by layer0/layer1)
#define O_OUT     46829568u   // 16384*1024 half (out0/out1 aliased; stream-ordered safe)
// total 80384000 bytes

// ---------------- fp32 -> fp16 convert (8 elems/thread) ----------------
__global__ void cvt_f32f16(const float* __restrict__ s, half_t* __restrict__ d, int n8) {
    int i = blockIdx.x * 256 + threadIdx.x;
    if (i < n8) {
        const float4* s4 = (const float4*)s;
        float4 a = s4[2*i], b = s4[2*i+1];
        half8 h;
        h[0]=(_Float16)a.x; h[1]=(_Float16)a.y; h[2]=(_Float16)a.z; h[3]=(_Float16)a.w;
        h[4]=(_Float16)b.x; h[5]=(_Float16)b.y; h[6]=(_Float16)b.z; h[7]=(_Float16)b.w;
        *(half8*)(d + (size_t)i*8) = h;
    }
}

// ---------------- generic NT GEMM: C[m,n] = sum_k A[m,k]*B[n,k] + bias ----------------
template<bool GATHER>
__global__ __launch_bounds__(256)
void gemm_nt(const half_t* __restrict__ A, const float* __restrict__ Atab,
             const int* __restrict__ gidx, const half_t* __restrict__ Bm,
             const float* __restrict__ bias0, const float* __restrict__ bias1,
             half_t* __restrict__ Cout, int M, int N, int K)
{
    __shared__ half8 As8[512];   // 128 x 32 half
    __shared__ half8 Bs8[512];
    half_t* As = (half_t*)As8;
    half_t* Bs = (half_t*)Bs8;

    const int tid  = threadIdx.x;
    const int lane = tid & 63, wid = tid >> 6;
    const int wm = wid >> 1, wn = wid & 1;
    const int ln = lane & 15, hi = lane >> 4;
    const int m0 = blockIdx.x * 128, n0 = blockIdx.y * 128;

    floatx4 acc[4][4] = {};
    const int kTiles = K >> 5;

    for (int kt = 0; kt < kTiles; ++kt) {
        if constexpr (GATHER) {
            int r = tid >> 1, q = tid & 1;
            int row = gidx[m0 + r];
            const float* src = Atab + (size_t)row * EMB + kt*32 + q*16;
            float4 f0 = *(const float4*)(src);
            float4 f1 = *(const float4*)(src + 4);
            float4 f2 = *(const float4*)(src + 8);
            float4 f3 = *(const float4*)(src + 12);
            half8 h0, h1;
            h0[0]=(_Float16)f0.x; h0[1]=(_Float16)f0.y; h0[2]=(_Float16)f0.z; h0[3]=(_Float16)f0.w;
            h0[4]=(_Float16)f1.x; h0[5]=(_Float16)f1.y; h0[6]=(_Float16)f1.z; h0[7]=(_Float16)f1.w;
            h1[0]=(_Float16)f2.x; h1[1]=(_Float16)f2.y; h1[2]=(_Float16)f2.z; h1[3]=(_Float16)f2.w;
            h1[4]=(_Float16)f3.x; h1[5]=(_Float16)f3.y; h1[6]=(_Float16)f3.z; h1[7]=(_Float16)f3.w;
            int c0 = 2*q, c1 = 2*q + 1;
            *(half8*)(As + r*32 + (((c0 + (r>>1)) & 3) * 8)) = h0;
            *(half8*)(As + r*32 + (((c1 + (r>>1)) & 3) * 8)) = h1;
        } else {
            #pragma unroll
            for (int ii = 0; ii < 2; ++ii) {
                int ch = tid + ii*256; int r = ch >> 2, c = ch & 3;
                half8 v = *(const half8*)(A + (size_t)(m0+r)*K + kt*32 + c*8);
                *(half8*)(As + r*32 + (((c + (r>>1)) & 3) * 8)) = v;
            }
        }
        #pragma unroll
        for (int ii = 0; ii < 2; ++ii) {
            int ch = tid + ii*256; int r = ch >> 2, c = ch & 3;
            half8 v = *(const half8*)(Bm + (size_t)(n0+r)*K + kt*32 + c*8);
            *(half8*)(Bs + r*32 + (((c + (r>>1)) & 3) * 8)) = v;
        }
        __syncthreads();

        half8 af[4], bf[4];
        #pragma unroll
        for (int mt = 0; mt < 4; ++mt) {
            int r = wm*64 + mt*16 + ln;
            af[mt] = *(const half8*)(As + r*32 + ((hi + (r>>1)) & 3) * 8);
        }
        #pragma unroll
        for (int nt = 0; nt < 4; ++nt) {
            int r = wn*64 + nt*16 + ln;
            bf[nt] = *(const half8*)(Bs + r*32 + ((hi + (r>>1)) & 3) * 8);
        }
        #pragma unroll
        for (int mt = 0; mt < 4; ++mt)
            #pragma unroll
            for (int nt = 0; nt < 4; ++nt)
                acc[mt][nt] = __builtin_amdgcn_mfma_f32_16x16x32_f16(af[mt], bf[nt], acc[mt][nt], 0, 0, 0);
        __syncthreads();
    }

    #pragma unroll
    for (int mt = 0; mt < 4; ++mt) {
        #pragma unroll
        for (int nt = 0; nt < 4; ++nt) {
            int n = n0 + wn*64 + nt*16 + ln;
            float bv = (bias0 ? bias0[n] : 0.f) + (bias1 ? bias1[n] : 0.f);
            #pragma unroll
            for (int r = 0; r < 4; ++r) {
                int m = m0 + wm*64 + mt*16 + hi*4 + r;
                Cout[(size_t)m*N + n] = (half_t)(acc[mt][nt][r] + bv);
            }
        }
    }
}

// ---------------- persistent bidirectional RNN layer (round 6: 2 waves/SIMD TLP) ----------------
// grid = 8 blocks (2 dir x 4 batch-groups) x 512 thr (8 waves, 2 per SIMD).
// Round-3 post-mortem: phases (MFMA 2500cy, LDS ~2700cy, VALU ~1200cy) were SERIAL because
// 1 wave/SIMD gives the scheduler nothing to overlap. Fix = TLP: 2 waves/SIMD, so one
// wave's LDS/VALU phase hides under the other's MFMA-pipe time (m114).
// Budget chase: 2 waves/SIMD -> 256 regs/wave -> afrag[4][12] (wave owns 64 j, k<384 in
// regs) -> W-tail 128 cols in LDS (139KB) -> h must be a SINGLE 16.6KB buffer updated
// in place with 2 barriers/step (read-all -> B1 -> write-own-slice -> B2).
// Step 0 is special-cased (h=0 -> acc=xq), so no h zero-init.
// s_setprio(1) wraps the MFMA cluster (T5: 2-wave arbitration now has role diversity).
__global__ __launch_bounds__(512, 2)
void rnn_layer(const half_t* __restrict__ xp, half_t* __restrict__ outbuf,
               const half_t* __restrict__ whh16)
{
    extern __shared__ char smem[];
    half_t* wlds = (half_t*)smem;                  // [512][WROW] W k-tail
    half_t* hlds = (half_t*)(smem + WLDS_BYTES);   // [16][HROW] single h buffer

    const int bid = blockIdx.x;
    const int dir = bid >> 2;
    const int bg  = bid & 3;
    const int w   = threadIdx.x >> 6;      // wave 0..7, owns j in [w*64, w*64+64)
    const int lane = threadIdx.x & 63;
    const int ln = lane & 15, hi = lane >> 4;

    const half_t* wbase = whh16 + (size_t)dir * HID * HID;

    // A fragments in regs: afrag[mt][kk] = W[w*64+mt*16+ln][kk*32+hi*8 ..+8], kk<12
    half8 afrag[4][KK_REG];
    #pragma unroll
    for (int mt = 0; mt < 4; ++mt) {
        #pragma unroll
        for (int kk = 0; kk < KK_REG; ++kk)
            afrag[mt][kk] = *(const half8*)(wbase + (size_t)(w*64 + mt*16 + ln)*HID + kk*32 + hi*8);
    }

    // stage W k-tail [384,512) into LDS: 512 rows x 16 half8
    for (int idx = threadIdx.x; idx < HID*16; idx += 512) {
        int row = idx >> 4, c8 = idx & 15;
        *(half8*)(wlds + row*WROW + c8*8) =
            *(const half8*)(wbase + (size_t)row*HID + K_REG + c8*8);
    }

    const int b  = bg*16 + ln;       // this lane's batch column
    const int jq = w*64 + hi*4;      // j quad base; mt adds 16

    const ptrdiff_t dstep = dir ? -(ptrdiff_t)(BATCH*2*HID) : (ptrdiff_t)(BATCH*2*HID);
    const int t0 = dir ? (SEQ-1) : 0;
    const size_t base0 = ((size_t)(t0*BATCH + b))*(2*HID) + (size_t)dir*HID + jq;
    const half_t* xb = xp + base0;
    half_t*       op = outbuf + base0;

    // per-lane LDS bases
    const half_t* hrd = hlds + (size_t)ln*HROW + hi*8;               // + kk*32 (tail: +K_REG+kt*32)
    half_t*       hwr = hlds + (size_t)ln*HROW + jq;                 // + mt*16
    const half_t* wrd = wlds + (size_t)(w*64 + ln)*WROW + hi*8;      // + mt*16*WROW + kt*32

    // ---- step 0: h == 0 -> acc = xq(t0); no h reads, no MFMA ----
    half4 xq[4];
    #pragma unroll
    for (int mt = 0; mt < 4; ++mt) xq[mt] = *(const half4*)(xb + mt*16);
    xb += dstep;

    floatx4 acc[4];
    #pragma unroll
    for (int mt = 0; mt < 4; ++mt) {
        acc[mt][0] = (float)xq[mt][0]; acc[mt][1] = (float)xq[mt][1];
        acc[mt][2] = (float)xq[mt][2]; acc[mt][3] = (float)xq[mt][3];
    }
    // prefetch xq(t1)
    #pragma unroll
    for (int mt = 0; mt < 4; ++mt) xq[mt] = *(const half4*)(xb + mt*16);
    xb += dstep;

    {
        half4 hv[4];
        #pragma unroll
        for (int mt = 0; mt < 4; ++mt) {
            #pragma unroll
            for (int r = 0; r < 4; ++r)
                hv[mt][r] = (_Float16)fmaxf(acc[mt][r], 0.f);
            *(half4*)(hwr + mt*16) = hv[mt];
            *(half4*)(op  + mt*16) = hv[mt];
        }
        op += dstep;
    }
    // covers: wlds staging + step-0 h writes, visible to all waves
    asm volatile("s_waitcnt lgkmcnt(0)\n\ts_barrier" ::: "memory");

    for (int step = 1; step < SEQ; ++step) {
        // seed acc from prefetched xq; issue next prefetch (lands under MFMA phase)
        #pragma unroll
        for (int mt = 0; mt < 4; ++mt) {
            acc[mt][0] = (float)xq[mt][0]; acc[mt][1] = (float)xq[mt][1];
            acc[mt][2] = (float)xq[mt][2]; acc[mt][3] = (float)xq[mt][3];
        }
        if (step + 1 < SEQ) {
            #pragma unroll
            for (int mt = 0; mt < 4; ++mt) xq[mt] = *(const half4*)(xb + mt*16);
        }
        xb += dstep;

        __builtin_amdgcn_s_setprio(1);
        // ---- k < 384: W in regs, h from LDS (2-deep paired pipeline) ----
        half8 c0 = *(const half8*)(hrd + 0*32);
        half8 c1 = *(const half8*)(hrd + 1*32);
        #pragma unroll
        for (int g = 0; g < 5; ++g) {
            half8 n0 = *(const half8*)(hrd + (2*g+2)*32);
            half8 n1 = *(const half8*)(hrd + (2*g+3)*32);
            #pragma unroll
            for (int mt = 0; mt < 4; ++mt)
                acc[mt] = __builtin_amdgcn_mfma_f32_16x16x32_f16(afrag[mt][2*g],   c0, acc[mt], 0, 0, 0);
            #pragma unroll
            for (int mt = 0; mt < 4; ++mt)
                acc[mt] = __builtin_amdgcn_mfma_f32_16x16x32_f16(afrag[mt][2*g+1], c1, acc[mt], 0, 0, 0);
            c0 = n0; c1 = n1;
        }
        #pragma unroll
        for (int mt = 0; mt < 4; ++mt)
            acc[mt] = __builtin_amdgcn_mfma_f32_16x16x32_f16(afrag[mt][10], c0, acc[mt], 0, 0, 0);
        #pragma unroll
        for (int mt = 0; mt < 4; ++mt)
            acc[mt] = __builtin_amdgcn_mfma_f32_16x16x32_f16(afrag[mt][11], c1, acc[mt], 0, 0, 0);

        // ---- k in [384,512): both W and h from LDS ----
        #pragma unroll
        for (int kt = 0; kt < 4; ++kt) {
            half8 ch = *(const half8*)(hrd + K_REG + kt*32);
            half8 w0 = *(const half8*)(wrd + 0*16*WROW + kt*32);
            half8 w1 = *(const half8*)(wrd + 1*16*WROW + kt*32);
            half8 w2 = *(const half8*)(wrd + 2*16*WROW + kt*32);
            half8 w3 = *(const half8*)(wrd + 3*16*WROW + kt*32);
            acc[0] = __builtin_amdgcn_mfma_f32_16x16x32_f16(w0, ch, acc[0], 0, 0, 0);
            acc[1] = __builtin_amdgcn_mfma_f32_16x16x32_f16(w1, ch, acc[1], 0, 0, 0);
            acc[2] = __builtin_amdgcn_mfma_f32_16x16x32_f16(w2, ch, acc[2], 0, 0, 0);
            acc[3] = __builtin_amdgcn_mfma_f32_16x16x32_f16(w3, ch, acc[3], 0, 0, 0);
        }
        __builtin_amdgcn_s_setprio(0);

        // ---- epilogue: hv = relu(acc) (VALU, overlaps other wave's reads) ----
        half4 hv[4];
        #pragma unroll
        for (int mt = 0; mt < 4; ++mt) {
            #pragma unroll
            for (int r = 0; r < 4; ++r)
                hv[mt][r] = (_Float16)fmaxf(acc[mt][r], 0.f);
        }

        if (step + 1 < SEQ) {
            // B1: every wave's h reads complete -> safe to overwrite in place
            asm volatile("s_waitcnt lgkmcnt(0)\n\ts_barrier" ::: "memory");
            #pragma unroll
            for (int mt = 0; mt < 4; ++mt)
                *(half4*)(hwr + mt*16) = hv[mt];
            // B2: h(t+1) visible to all waves
            asm volatile("s_waitcnt lgkmcnt(0)\n\ts_barrier" ::: "memory");
        }

        // fire-and-forget global store (drained at kernel end)
        #pragma unroll
        for (int mt = 0; mt < 4; ++mt)
            *(half4*)(op + mt*16) = hv[mt];
        op += dstep;
    }
}

// ---------------- final FC: [16384,1024] x [18,1024]^T + b ----------------
__global__ __launch_bounds__(256)
void fc_kernel(const half_t* __restrict__ X, const half_t* __restrict__ W16,
               const float* __restrict__ bias, float* __restrict__ Y)
{
    __shared__ half8 Ws8[2304];   // 18*1024 half
    half_t* Ws = (half_t*)Ws8;
    for (int ch = threadIdx.x; ch < 2304; ch += 256)
        Ws8[ch] = *(const half8*)(W16 + (size_t)ch*8);
    __syncthreads();

    int wi = threadIdx.x >> 6, lane = threadIdx.x & 63;
    int m = blockIdx.x*4 + wi;
    const half_t* xr = X + (size_t)m*1024 + lane*16;
    half8 x0 = *(const half8*)xr;
    half8 x1 = *(const half8*)(xr + 8);
    float xa[16];
    #pragma unroll
    for (int i = 0; i < 8; ++i) { xa[i] = (float)x0[i]; xa[8+i] = (float)x1[i]; }

    for (int n = 0; n < NOUT; ++n) {
        const half_t* wr = Ws + n*1024 + lane*16;
        half8 w0 = *(const half8*)wr;
        half8 w1 = *(const half8*)(wr + 8);
        float s = 0.f;
        #pragma unroll
        for (int i = 0; i < 8; ++i) s += xa[i]*(float)w0[i] + xa[8+i]*(float)w1[i];
        #pragma unroll
        for (int off = 32; off > 0; off >>= 1) s += __shfl_down(s, off, 64);
        if (lane == 0) Y[(size_t)m*NOUT + n] = s + bias[n];
    }
}

// ---------------- launcher ----------------
extern "C" void kernel_launch(void* const* d_in, const int* in_sizes, int n_in,
                              void* d_out, int out_size, void* d_ws, size_t ws_size,
                              hipStream_t stream)
{
    const int*   text    = (const int*)  d_in[0];
    const float* emb     = (const float*)d_in[1];
    const float* emfc_w  = (const float*)d_in[2];
    const float* emfc_b  = (const float*)d_in[3];
    const float* w_ih0   = (const float*)d_in[4];
    const float* w_hh0   = (const float*)d_in[5];
    const float* b_ih0   = (const float*)d_in[6];
    const float* b_hh0   = (const float*)d_in[7];
    const float* w_ih1   = (const float*)d_in[8];
    const float* w_hh1   = (const float*)d_in[9];
    const float* b_ih1   = (const float*)d_in[10];
    const float* b_hh1   = (const float*)d_in[11];
    const float* fc_w    = (const float*)d_in[12];
    const float* fc_b    = (const float*)d_in[13];
    float* out = (float*)d_out;

    char* ws = (char*)d_ws;
    half_t* whh0_16 = (half_t*)(ws + O_WHH0_16);
    half_t* whh1_16 = (half_t*)(ws + O_WHH1_16);
    half_t* emfc16  = (half_t*)(ws + O_EMFC16);
    half_t* wih0    = (half_t*)(ws + O_WIH0);
    half_t* wih1    = (half_t*)(ws + O_WIH1);
    half_t* fc16    = (half_t*)(ws + O_FC16);
    half_t* pe      = (half_t*)(ws + O_PE);
    half_t* xp      = (half_t*)(ws + O_XP);
    half_t* out0    = (half_t*)(ws + O_OUT);
    half_t* out1    = (half_t*)(ws + O_OUT);   // aliased: out0 dead once xp1 GEMM done

    // one-time: allow 152.3KB dynamic LDS for rnn_layer (host-side attr; capture-safe)
    static int attr_done = 0;
    if (!attr_done) {
        hipFuncSetAttribute((const void*)rnn_layer,
                            hipFuncAttributeMaxDynamicSharedMemorySize, LDS_BYTES);
        attr_done = 1;
    }

    // 1) weight conversions fp32->fp16
    cvt_f32f16<<<32,  256, 0, stream>>>(emfc_w, emfc16, 8192);
    cvt_f32f16<<<128, 256, 0, stream>>>(w_ih0,  wih0,  32768);
    cvt_f32f16<<<512, 256, 0, stream>>>(w_ih1,  wih1, 131072);
    cvt_f32f16<<<256, 256, 0, stream>>>(w_hh0,  whh0_16, 65536);
    cvt_f32f16<<<256, 256, 0, stream>>>(w_hh1,  whh1_16, 65536);
    cvt_f32f16<<<9,   256, 0, stream>>>(fc_w,   fc16,   2304);

    // 2) post_emb = gather(emb, text) @ emfc_w^T + emfc_b
    gemm_nt<true><<<dim3(M_TOT/128, EMB/128), 256, 0, stream>>>(
        nullptr, emb, text, emfc16, emfc_b, nullptr, pe, M_TOT, EMB, EMB);

    // 3) xp0 = post_emb @ w_ih0^T + (b_ih0 + b_hh0)
    gemm_nt<false><<<dim3(M_TOT/128, (2*HID)/128), 256, 0, stream>>>(
        pe, nullptr, nullptr, wih0, b_ih0, b_hh0, xp, M_TOT, 2*HID, EMB);

    // 4) layer0 recurrence (8 independent blocks x 8 waves)
    rnn_layer<<<8, 512, LDS_BYTES, stream>>>(xp, out0, whh0_16);

    // 5) xp1 = out0 @ w_ih1^T + (b_ih1 + b_hh1)
    gemm_nt<false><<<dim3(M_TOT/128, (2*HID)/128), 256, 0, stream>>>(
        out0, nullptr, nullptr, wih1, b_ih1, b_hh1, xp, M_TOT, 2*HID, 2*HID);

    // 6) layer1 recurrence
    rnn_layer<<<8, 512, LDS_BYTES, stream>>>(xp, out1, whh1_16);

    // 7) out = out1 @ fc_w^T + fc_b
    fc_kernel<<<M_TOT/4, 256, 0, stream>>>(out1, fc16, fc_b, out);
}